// Round 4
// baseline (130.410 us; speedup 1.0000x reference)
//
#include <hip/hip_runtime.h>

// ---------- bf16 helpers (raw ushort representation) ----------
__device__ __forceinline__ unsigned short f2b(float f) {
    unsigned int u = __builtin_bit_cast(unsigned int, f);
    u += 0x7fffu + ((u >> 16) & 1u);   // round-to-nearest-even
    return (unsigned short)(u >> 16);
}

typedef short bf16x8_t __attribute__((ext_vector_type(8)));
typedef float f32x4_t  __attribute__((ext_vector_type(4)));

#define LDS_PTR(p) ((__attribute__((address_space(3))) void*)(p))
#define GLB_PTR(p) ((const __attribute__((address_space(1))) void*)(p))

// Problem dims
#define NB   16384   // batch
#define AD   1024    // A dim
#define YD   128     // output dim
#define ND   256     // GEMM N = 2*YD
#define BM   32      // gemm M-tile

// =====================================================================
// Kernel 1 (fused): blocks [0, 4096): row moments -> bf fixed point -> bff.
//                   blocks [4096, 5120): Vt[n][a] = Kp[a,j]*u[2a+j][y] (bf16).
// Row math identical to round-2/3 validated version; afb write removed.
// =====================================================================
__global__ __launch_bounds__(256) void rowvt_kernel(
    const float* __restrict__ AT,    // [16384][1024] f32
    const float* __restrict__ Kq,    // [1024][2] f32
    const float* __restrict__ BTv,   // [2] f32
    const float* __restrict__ U,     // [2048][128] f32
    unsigned short* __restrict__ Vt, // [256][1024] bf16 out
    float* __restrict__ bff)         // [16384][2] f32 out
{
    int bx = blockIdx.x;
    if (bx >= NB / 4) {
        // ---- vt part ----
        int idx = (bx - NB / 4) * 256 + threadIdx.x;   // 0 .. 262143
        int n = idx >> 10;
        int a = idx & 1023;
        int j = n >> 7;
        int y = n & 127;
        float k  = Kq[2 * a + j];
        float uv = U[(size_t)(2 * a + j) * YD + y];
        Vt[idx] = f2b(k * k * uv);
        return;
    }
    // ---- row part: one wave per row ----
    int wid  = bx * 4 + (threadIdx.x >> 6);
    int lane = threadIdx.x & 63;
    const float* at = AT + (size_t)wid * AD;

    float ta[16], kp0[16], kp1[16];
#pragma unroll
    for (int c = 0; c < 4; ++c) {
        int base = c * 256 + lane * 4;
        float4 av = *(const float4*)(at + base);
        ta[c * 4 + 0] = av.x; ta[c * 4 + 1] = av.y;
        ta[c * 4 + 2] = av.z; ta[c * 4 + 3] = av.w;
        float4 k0 = *(const float4*)(Kq + 2 * base);
        float4 k1 = *(const float4*)(Kq + 2 * base + 4);
        kp0[c * 4 + 0] = k0.x * k0.x; kp1[c * 4 + 0] = k0.y * k0.y;
        kp0[c * 4 + 1] = k0.z * k0.z; kp1[c * 4 + 1] = k0.w * k0.w;
        kp0[c * 4 + 2] = k1.x * k1.x; kp1[c * 4 + 2] = k1.y * k1.y;
        kp0[c * 4 + 3] = k1.z * k1.z; kp1[c * 4 + 3] = k1.w * k1.w;
    }

    // moments: 0:M0 1:M1 2:M00 3:M01 4:M11 5:M000 6:M001 7:M011 8:M111
    float M[9];
#pragma unroll
    for (int i = 0; i < 9; ++i) M[i] = 0.f;
#pragma unroll
    for (int e = 0; e < 16; ++e) {
        float t = ta[e], p = kp0[e], q = kp1[e];
        float u0 = t * p, u1 = t * q;
        M[0] += u0; M[1] += u1;
        float u00 = u0 * p, u01 = u0 * q, u11 = u1 * q;
        M[2] += u00; M[3] += u01; M[4] += u11;
        M[5] += u00 * p; M[6] += u00 * q; M[7] += u01 * q; M[8] += u11 * q;
    }
#pragma unroll
    for (int i = 0; i < 9; ++i) {
        for (int m = 1; m < 64; m <<= 1) M[i] += __shfl_xor(M[i], m, 64);
    }

    float bt0 = BTv[0], bt1 = BTv[1];
    float bf0 = 0.f, bf1 = 0.f;
#pragma unroll
    for (int it = 0; it < 8; ++it) {
        float q00 = bf0 * bf0, q01 = bf0 * bf1, q11 = bf1 * bf1;
        float s0 = M[0] - (bf0 * M[2] + bf1 * M[3]) + (q00 * M[5] + 2.f * q01 * M[6] + q11 * M[7]);
        float s1 = M[1] - (bf0 * M[3] + bf1 * M[4]) + (q00 * M[6] + 2.f * q01 * M[7] + q11 * M[8]);
        bf0 = bt0 / (1.f + s0);
        bf1 = bt1 / (1.f + s1);
    }
    if (lane == 0) { bff[(size_t)wid * 2] = bf0; bff[(size_t)wid * 2 + 1] = bf1; }
}

// =====================================================================
// Kernel 2: fused weighted-GEMM + combine, reading raw AT (f32, L3-warm).
//   af[m][k] = AT[m][k] * w,  w = 1 - x + x^2 = x*(x-1)+1,
//   x = bf0[m]*kp0[k] + bf1[m]*kp1[k]   (x <= 0.012, poly err ~2e-6 rel)
//   out[m][y] = bf0[m]*G[m][y] + bf1[m]*G[m][y+128] + bias[y]
// BM=32, BN=256(full), BK=64; 512 blocks, 256 threads (4 waves = 4 n-groups).
// A converted cooperatively once per tile through 4 KB LDS (XOR chunk swizzle);
// B staged via global_load_lds width=16 from L2.
// =====================================================================
__global__ __launch_bounds__(256) void gemm_fused_kernel(
    const float* __restrict__ AT,          // [16384][1024] f32
    const float* __restrict__ Kq,          // [1024][2] f32
    const unsigned short* __restrict__ Bg, // Vt [256][1024] bf16
    const float* __restrict__ bff,         // [16384][2]
    const float* __restrict__ bias,        // [128]
    float* __restrict__ out)               // [16384][128] f32
{
    __shared__ __align__(16) unsigned short lA[BM * 64];    // 4 KB
    __shared__ __align__(16) unsigned short lB[256 * 64];   // 32 KB
    __shared__ __align__(16) float kpp[2 * AD];             // 8 KB: [2k]=kp0, [2k+1]=kp1

    const int t = threadIdx.x;
    const int lane = t & 63;
    const int wn = t >> 6;
    const int mtile = blockIdx.x;   // 0..511

    // kpp = Kq^2 elementwise (layout matches: kpp[2a+j] = K[a][j]^2)
#pragma unroll
    for (int i = 0; i < 8; ++i) {
        int id = i * 256 + t;
        float kv = Kq[id];
        kpp[id] = kv * kv;
    }

    // A-conversion mapping: thread t -> row crow = t>>3, chunk cch = t&7
    const int crow = t >> 3;
    const int cch  = t & 7;
    const float* aRow = AT + (size_t)(mtile * BM + crow) * AD + cch * 8;
    const float2 cbf = *(const float2*)(bff + (size_t)(mtile * BM + crow) * 2);
    const int cbyte = (crow * 8 + (cch ^ (crow & 7))) * 8;  // swizzled chunk slot (ushort idx)

    // B staging pointers (slot s -> row n = s>>3, chunk c = (s&7)^(n&7))
    const unsigned short* gB[8];
#pragma unroll
    for (int i = 0; i < 8; ++i) {
        int s = i * 256 + t;
        int n = s >> 3;
        int c = (s & 7) ^ (n & 7);
        gB[i] = Bg + (size_t)n * AD + 8 * c;
    }

    f32x4_t acc[2][4];
#pragma unroll
    for (int i = 0; i < 2; ++i)
#pragma unroll
        for (int j = 0; j < 4; ++j) acc[i][j] = (f32x4_t){0.f, 0.f, 0.f, 0.f};

    __syncthreads();   // kpp ready

    for (int k0 = 0; k0 < AD; k0 += 64) {
        // B: async global->LDS
#pragma unroll
        for (int i = 0; i < 8; ++i)
            __builtin_amdgcn_global_load_lds(GLB_PTR(gB[i] + k0), LDS_PTR(&lB[(i * 256 + t) * 8]), 16, 0, 0);

        // A: load f32, weight, convert, store bf16 chunk to LDS
        {
            float4 a0 = *(const float4*)(aRow + k0);
            float4 a1 = *(const float4*)(aRow + k0 + 4);
            const float* kp = &kpp[2 * (k0 + cch * 8)];
            float4 p0 = *(const float4*)(kp);       // [p(k),q(k),p(k+1),q(k+1)]
            float4 p1 = *(const float4*)(kp + 4);
            float4 p2 = *(const float4*)(kp + 8);
            float4 p3 = *(const float4*)(kp + 12);
            float av[8] = {a0.x, a0.y, a0.z, a0.w, a1.x, a1.y, a1.z, a1.w};
            float pv[8] = {p0.x, p0.z, p1.x, p1.z, p2.x, p2.z, p3.x, p3.z};
            float qv[8] = {p0.y, p0.w, p1.y, p1.w, p2.y, p2.w, p3.y, p3.w};
            unsigned int pk[4];
#pragma unroll
            for (int e = 0; e < 4; ++e) {
                float x0 = cbf.x * pv[2 * e]     + cbf.y * qv[2 * e];
                float x1 = cbf.x * pv[2 * e + 1] + cbf.y * qv[2 * e + 1];
                float w0 = x0 * (x0 - 1.f) + 1.f;     // 1 - x + x^2
                float w1 = x1 * (x1 - 1.f) + 1.f;
                unsigned short lo = f2b(av[2 * e] * w0);
                unsigned short hi = f2b(av[2 * e + 1] * w1);
                pk[e] = (unsigned int)lo | ((unsigned int)hi << 16);
            }
            *(uint4*)(&lA[cbyte]) = make_uint4(pk[0], pk[1], pk[2], pk[3]);
        }
        __syncthreads();   // lA writes + lB async loads drained

#pragma unroll
        for (int kk = 0; kk < 2; ++kk) {
            const int cq = kk * 4 + (lane >> 4);
            const int rr = lane & 15;
            bf16x8_t fa[2], fb[4];
#pragma unroll
            for (int i = 0; i < 2; ++i) {
                int m = i * 16 + rr;
                fa[i] = *(const bf16x8_t*)(&lA[(m * 8 + (cq ^ (m & 7))) * 8]);
            }
#pragma unroll
            for (int j = 0; j < 4; ++j) {
                int n = wn * 32 + (j & 1) * 16 + (j >> 1) * 128 + rr;
                fb[j] = *(const bf16x8_t*)(&lB[(n * 8 + (cq ^ (n & 7))) * 8]);
            }
#pragma unroll
            for (int i = 0; i < 2; ++i)
#pragma unroll
                for (int j = 0; j < 4; ++j)
                    acc[i][j] = __builtin_amdgcn_mfma_f32_16x16x32_bf16(fa[i], fb[j], acc[i][j], 0, 0, 0);
        }
        __syncthreads();
    }

    // epilogue: C/D layout col=lane&15 (n), row=(lane>>4)*4+reg (m)
    const int q = lane >> 4, col = lane & 15;
#pragma unroll
    for (int i = 0; i < 2; ++i) {
        int mbase = mtile * BM + i * 16 + q * 4;
        float2 bfv[4];
#pragma unroll
        for (int r = 0; r < 4; ++r)
            bfv[r] = *(const float2*)(bff + (size_t)(mbase + r) * 2);
#pragma unroll
        for (int j = 0; j < 2; ++j) {
            int y = wn * 32 + j * 16 + col;
            float bv = bias[y];
#pragma unroll
            for (int r = 0; r < 4; ++r) {
                float val = bfv[r].x * acc[i][j][r] + bfv[r].y * acc[i][j + 2][r] + bv;
                out[(size_t)(mbase + r) * YD + y] = val;
            }
        }
    }
}

// =====================================================================
extern "C" void kernel_launch(void* const* d_in, const int* in_sizes, int n_in,
                              void* d_out, int out_size, void* d_ws, size_t ws_size,
                              hipStream_t stream) {
    const float* AT  = (const float*)d_in[0];  // [16384][1024] f32
    const float* Kq  = (const float*)d_in[1];  // [1024][2] f32
    const float* BTv = (const float*)d_in[2];  // [2] f32
    const float* U   = (const float*)d_in[3];  // [2048][128] f32
    const float* bia = (const float*)d_in[4];  // [128] f32
    float* out = (float*)d_out;

    char* ws = (char*)d_ws;
    unsigned short* Vt  = (unsigned short*)(ws);           // 512 KB bf16 [256][1024]
    float*          bff = (float*)(ws + 524288);           // 128 KB f32  [16384][2]
    // total ws usage ~640 KB

    rowvt_kernel<<<dim3(NB / 4 + 1024), dim3(256), 0, stream>>>(AT, Kq, BTv, U, Vt, bff);
    gemm_fused_kernel<<<dim3(NB / BM), dim3(256), 0, stream>>>(AT, Kq, Vt, bff, bia, out);
}